// Round 9
// baseline (303.331 us; speedup 1.0000x reference)
//
#include <hip/hip_runtime.h>
#include <math.h>

// Model: B=32, C=64, T=1024, H=10, OUT=2.
// ONE kernel, 32 blocks (one per batch element) x 512 threads; each thread
// owns TWO time-steps (t, t+512). S1 embed | S2 bn+tanh + qkv stats |
// S3 M=KV^T in TWO sequential passes (a then b) | S4 N=M Wc^T/H, recompute
// q -> prec=q.N | S5 bn+relu -> Iin into LDS | S6 LSNN scan on wave 0.
// Cross-block: BN batch stats (3x) via agent-scope atomics + 32-block barrier.
//
// R8 post-mortem: VGPR budget correctly 128 (512-thr blocks), but S3's
// doubled working set (~80 live floats) still spilled ~510 B/thread
// (WRITE_SIZE 8.2 MB). R9: recompute-everything -- M in two passes (only
// one pass's kx/vx live), qv recomputed inside S4 (qva/qvb never stored),
// only xa/xb (20 floats) carried across barriers. Peak live ~60 < 128.

constexpr int B = 32, C = 64, T = 1024, H = 10;
constexpr int NT = 512;   // threads per block (8 waves)

struct Params {
  const float *beeg, *W_ef, *b_ef, *g_i, *be_i, *Wq, *g_q, *be_q, *Wk, *g_k,
      *be_k, *Wv, *g_v, *be_v, *Wc, *g_c, *be_c, *W_in, *W_rec, *W_cls, *b_cls;
  int* cnt;              // barrier counters (memset 0 each launch)
  double *P1, *P2, *P3;  // cross-block stat partials
  float* out;
};

__device__ inline float wred(float v) {
#pragma unroll
  for (int o = 32; o; o >>= 1) v += __shfl_down(v, o, 64);
  return v;
}

// 32-block device-scope barrier (release/acquire on counter orders partials).
__device__ inline void gbar(int* cnt, int phase, int tid) {
  __syncthreads();
  if (tid == 0) {
    __threadfence();
    __hip_atomic_fetch_add(&cnt[phase], 1, __ATOMIC_RELEASE,
                           __HIP_MEMORY_SCOPE_AGENT);
    while (__hip_atomic_load(&cnt[phase], __ATOMIC_ACQUIRE,
                             __HIP_MEMORY_SCOPE_AGENT) < B)
      __builtin_amdgcn_s_sleep(1);
    __threadfence();
  }
  __syncthreads();
}

// wlds layout (floats)
#define WEF 0      // 640: W_ef
#define WQ  640    // 100
#define WK  740    // 100
#define WV  840    // 100
#define WC  940    // 100
#define WIN 1040   // 100
#define GI  1140
#define BEI 1150
#define GQ  1160
#define BEQ 1170
#define GK  1180
#define BEK 1190
#define GV  1200
#define BEV 1210
#define GC  1220
#define BEC 1230
#define BEF 1240   // 10

__global__ void __launch_bounds__(NT) fused6(Params p) {
  const int b = blockIdx.x, tid = threadIdx.x;
  const int lane = tid & 63, wid = tid >> 6;   // 8 waves
  const int t0 = tid, t1 = tid + NT;

  __shared__ __align__(16) float slab[T * 11];  // 45056 B: scratch then Iin
  __shared__ __align__(16) float gtab[T];       // 4 KB
  __shared__ float wlds[1250 + 16];             // staged weights/params
  __shared__ double dtot[60];
  __shared__ float stM[30], stI[30], Ms[100], Nl[100];

  float* swred = slab;         // [8][60] stats scratch (dead before S5)
  float* mpw   = slab + 512;   // [8][100] M partials (dead before S5)

  // ---------------- stage all small weights into LDS
  for (int i = tid; i < 640; i += NT) wlds[WEF + i] = p.W_ef[i];
  if (tid < 100) {
    wlds[WQ + tid]  = p.Wq[tid];
    wlds[WK + tid]  = p.Wk[tid];
    wlds[WV + tid]  = p.Wv[tid];
    wlds[WC + tid]  = p.Wc[tid];
    wlds[WIN + tid] = p.W_in[tid];
  }
  if (tid < 10) {
    wlds[GI + tid]  = p.g_i[tid];  wlds[BEI + tid] = p.be_i[tid];
    wlds[GQ + tid]  = p.g_q[tid];  wlds[BEQ + tid] = p.be_q[tid];
    wlds[GK + tid]  = p.g_k[tid];  wlds[BEK + tid] = p.be_k[tid];
    wlds[GV + tid]  = p.g_v[tid];  wlds[BEV + tid] = p.be_v[tid];
    wlds[GC + tid]  = p.g_c[tid];  wlds[BEC + tid] = p.be_c[tid];
    wlds[BEF + tid] = p.b_ef[tid];
  }
  __syncthreads();

  // ---------------- S1: embed (two t's per thread)
  float p1a[H], p1b[H];
#pragma unroll
  for (int h = 0; h < H; ++h) { p1a[h] = wlds[BEF + h]; p1b[h] = wlds[BEF + h]; }
  {
    const float* bp = p.beeg + (size_t)b * C * T;
    for (int c = 0; c < C; ++c) {
      float va = bp[(size_t)c * T + t0];
      float vb = bp[(size_t)c * T + t1];
#pragma unroll
      for (int h = 0; h < H; ++h) {
        float w = wlds[WEF + h * C + c];
        p1a[h] = fmaf(va, w, p1a[h]);
        p1b[h] = fmaf(vb, w, p1b[h]);
      }
    }
  }
#pragma unroll
  for (int h = 0; h < H; ++h) {
    float r1 = wred(p1a[h] + p1b[h]);
    float r2 = wred(p1a[h] * p1a[h] + p1b[h] * p1b[h]);
    if (lane == 0) { swred[wid * 60 + h] = r1; swred[wid * 60 + 10 + h] = r2; }
  }
  __syncthreads();
  if (tid < 20) {
    double s = 0.0;
#pragma unroll
    for (int w = 0; w < 8; ++w) s += (double)swred[w * 60 + tid];
    __hip_atomic_store(&p.P1[b * 20 + tid], s, __ATOMIC_RELAXED,
                       __HIP_MEMORY_SCOPE_AGENT);
  }
  gbar(p.cnt, 0, tid);
  if (tid < 20) {
    double s = 0.0;
    for (int i = 0; i < B; ++i)
      s += __hip_atomic_load(&p.P1[i * 20 + tid], __ATOMIC_RELAXED,
                             __HIP_MEMORY_SCOPE_AGENT);
    dtot[tid] = s;
  }
  __syncthreads();
  if (tid < 10) {
    double mean = dtot[tid] * (1.0 / 32768.0);
    double var  = dtot[10 + tid] * (1.0 / 32768.0) - mean * mean;
    stM[tid] = (float)mean;
    stI[tid] = (float)(1.0 / sqrt(var + 1e-5));
  }
  __syncthreads();

  // ---------------- S2: x = tanh(bn(pre1)); qkv stats (accumulators only)
  float xa[H], xb[H];
#pragma unroll
  for (int j = 0; j < H; ++j) {
    xa[j] = tanhf(wlds[GI + j] * (p1a[j] - stM[j]) * stI[j] + wlds[BEI + j]);
    xb[j] = tanhf(wlds[GI + j] * (p1b[j] - stM[j]) * stI[j] + wlds[BEI + j]);
  }
  // p1a/p1b dead; only xa/xb (20 floats) persist from here on.
#pragma unroll
  for (int h = 0; h < H; ++h) {
    float qa = 0.f, qb = 0.f, ka = 0.f, kb = 0.f, va = 0.f, vb = 0.f;
#pragma unroll
    for (int j = 0; j < H; ++j) {
      float wq = wlds[WQ + h * H + j], wk = wlds[WK + h * H + j],
            wv = wlds[WV + h * H + j];
      qa = fmaf(xa[j], wq, qa); qb = fmaf(xb[j], wq, qb);
      ka = fmaf(xa[j], wk, ka); kb = fmaf(xb[j], wk, kb);
      va = fmaf(xa[j], wv, va); vb = fmaf(xb[j], wv, vb);
    }
    float r1 = wred(qa + qb), r2 = wred(qa * qa + qb * qb);
    float r3 = wred(ka + kb), r4 = wred(ka * ka + kb * kb);
    float r5 = wred(va + vb), r6 = wred(va * va + vb * vb);
    if (lane == 0) {
      swred[wid * 60 + h]      = r1; swred[wid * 60 + 30 + h] = r2;
      swred[wid * 60 + 10 + h] = r3; swred[wid * 60 + 40 + h] = r4;
      swred[wid * 60 + 20 + h] = r5; swred[wid * 60 + 50 + h] = r6;
    }
  }
  __syncthreads();
  if (tid < 60) {
    double s = 0.0;
#pragma unroll
    for (int w = 0; w < 8; ++w) s += (double)swred[w * 60 + tid];
    __hip_atomic_store(&p.P2[b * 60 + tid], s, __ATOMIC_RELAXED,
                       __HIP_MEMORY_SCOPE_AGENT);
  }
  gbar(p.cnt, 1, tid);
  if (tid < 60) {
    double s = 0.0;
    for (int i = 0; i < B; ++i)
      s += __hip_atomic_load(&p.P2[i * 60 + tid], __ATOMIC_RELAXED,
                             __HIP_MEMORY_SCOPE_AGENT);
    dtot[tid] = s;
  }
  __syncthreads();
  if (tid < 30) {
    double mean = dtot[tid] * (1.0 / 32768.0);
    double var  = dtot[30 + tid] * (1.0 / 32768.0) - mean * mean;
    stM[tid] = (float)mean;
    stI[tid] = (float)(1.0 / sqrt(var + 1e-5));
  }
  __syncthreads();

  // ---------------- S3: M = KV^T in two sequential passes (low pressure)
  {  // pass a
    float kx[H], vx[H];
#pragma unroll
    for (int h = 0; h < H; ++h) {
      float ka = 0.f, va = 0.f;
#pragma unroll
      for (int j = 0; j < H; ++j) {
        ka = fmaf(xa[j], wlds[WK + h * H + j], ka);
        va = fmaf(xa[j], wlds[WV + h * H + j], va);
      }
      kx[h] = fmaxf(wlds[GK + h] * (ka - stM[10 + h]) * stI[10 + h] + wlds[BEK + h], 0.f);
      vx[h] = tanhf(wlds[GV + h] * (va - stM[20 + h]) * stI[20 + h] + wlds[BEV + h]);
    }
#pragma unroll
    for (int i = 0; i < H; ++i)
#pragma unroll
      for (int j = 0; j < H; ++j) {
        float r = wred(kx[i] * vx[j]);
        if (lane == 0) mpw[wid * 100 + i * 10 + j] = r;
      }
  }
  {  // pass b (accumulate)
    float kx[H], vx[H];
#pragma unroll
    for (int h = 0; h < H; ++h) {
      float kb = 0.f, vb = 0.f;
#pragma unroll
      for (int j = 0; j < H; ++j) {
        kb = fmaf(xb[j], wlds[WK + h * H + j], kb);
        vb = fmaf(xb[j], wlds[WV + h * H + j], vb);
      }
      kx[h] = fmaxf(wlds[GK + h] * (kb - stM[10 + h]) * stI[10 + h] + wlds[BEK + h], 0.f);
      vx[h] = tanhf(wlds[GV + h] * (vb - stM[20 + h]) * stI[20 + h] + wlds[BEV + h]);
    }
#pragma unroll
    for (int i = 0; i < H; ++i)
#pragma unroll
      for (int j = 0; j < H; ++j) {
        float r = wred(kx[i] * vx[j]);
        if (lane == 0) mpw[wid * 100 + i * 10 + j] += r;
      }
  }
  __syncthreads();
  if (tid < 100) {
    float s = 0.f;
#pragma unroll
    for (int w = 0; w < 8; ++w) s += mpw[w * 100 + tid];
    Ms[tid] = s;
  }
  __syncthreads();

  // ---------------- S4: N = (M Wc^T)/H; recompute q; prec = q . N
  if (tid < 100) {
    int i = tid / 10, h = tid % 10;
    float a = 0.f;
#pragma unroll
    for (int j = 0; j < H; ++j) a = fmaf(Ms[i * 10 + j], wlds[WC + h * H + j], a);
    Nl[tid] = a * 0.1f;
  }
  __syncthreads();
  float pca[H], pcb[H];
  {  // pass a
    float qv[H];
#pragma unroll
    for (int h = 0; h < H; ++h) {
      float qa = 0.f;
#pragma unroll
      for (int j = 0; j < H; ++j) qa = fmaf(xa[j], wlds[WQ + h * H + j], qa);
      qv[h] = fmaxf(wlds[GQ + h] * (qa - stM[h]) * stI[h] + wlds[BEQ + h], 0.f);
    }
#pragma unroll
    for (int h = 0; h < H; ++h) {
      float a = 0.f;
#pragma unroll
      for (int i = 0; i < H; ++i) a = fmaf(qv[i], Nl[i * 10 + h], a);
      pca[h] = a;
    }
  }
  {  // pass b
    float qv[H];
#pragma unroll
    for (int h = 0; h < H; ++h) {
      float qb = 0.f;
#pragma unroll
      for (int j = 0; j < H; ++j) qb = fmaf(xb[j], wlds[WQ + h * H + j], qb);
      qv[h] = fmaxf(wlds[GQ + h] * (qb - stM[h]) * stI[h] + wlds[BEQ + h], 0.f);
    }
#pragma unroll
    for (int h = 0; h < H; ++h) {
      float a = 0.f;
#pragma unroll
      for (int i = 0; i < H; ++i) a = fmaf(qv[i], Nl[i * 10 + h], a);
      pcb[h] = a;
    }
  }
  // xa/xb dead now; pca/pcb (20 floats) live.
#pragma unroll
  for (int h = 0; h < H; ++h) {
    float r1 = wred(pca[h] + pcb[h]);
    float r2 = wred(pca[h] * pca[h] + pcb[h] * pcb[h]);
    if (lane == 0) { swred[wid * 60 + h] = r1; swred[wid * 60 + 10 + h] = r2; }
  }
  __syncthreads();
  if (tid < 20) {
    double s = 0.0;
#pragma unroll
    for (int w = 0; w < 8; ++w) s += (double)swred[w * 60 + tid];
    __hip_atomic_store(&p.P3[b * 20 + tid], s, __ATOMIC_RELAXED,
                       __HIP_MEMORY_SCOPE_AGENT);
  }
  gbar(p.cnt, 2, tid);
  if (tid < 20) {
    double s = 0.0;
    for (int i = 0; i < B; ++i)
      s += __hip_atomic_load(&p.P3[i * 20 + tid], __ATOMIC_RELAXED,
                             __HIP_MEMORY_SCOPE_AGENT);
    dtot[tid] = s;
  }
  __syncthreads();
  if (tid < 10) {
    double mean = dtot[tid] * (1.0 / 32768.0);
    double var  = dtot[10 + tid] * (1.0 / 32768.0) - mean * mean;
    stM[tid] = (float)mean;
    stI[tid] = (float)(1.0 / sqrt(var + 1e-5));
  }
  __syncthreads();   // all slab-scratch reads done before S5 overwrites

  // ---------------- S5: bn+relu, Iin into LDS slab (stride 11); f32 g-table
  {
    float ca[H];
#pragma unroll
    for (int j = 0; j < H; ++j)
      ca[j] = fmaxf(wlds[GC + j] * (pca[j] - stM[j]) * stI[j] + wlds[BEC + j], 0.f);
#pragma unroll
    for (int h = 0; h < H; ++h) {
      float a = 0.f;
#pragma unroll
      for (int j = 0; j < H; ++j) a = fmaf(ca[j], wlds[WIN + h * H + j], a);
      slab[t0 * 11 + h] = a;
    }
#pragma unroll
    for (int j = 0; j < H; ++j)
      ca[j] = fmaxf(wlds[GC + j] * (pcb[j] - stM[j]) * stI[j] + wlds[BEC + j], 0.f);
#pragma unroll
    for (int h = 0; h < H; ++h) {
      float a = 0.f;
#pragma unroll
      for (int j = 0; j < H; ++j) a = fmaf(ca[j], wlds[WIN + h * H + j], a);
      slab[t1 * 11 + h] = a;
    }
    // g[t] = (9(1-0.9^{T-t}) - 4(1-0.8^{T-t})) / T
    const float L2A = -0.15200309344504995f;   // log2(0.9)
    const float L2D = -0.32192809488736235f;   // log2(0.8)
    float m0 = (float)(T - t0), m1 = (float)(T - t1);
    gtab[t0] = (9.0f * (1.0f - exp2f(m0 * L2A)) -
                4.0f * (1.0f - exp2f(m0 * L2D))) * (1.0f / (float)T);
    gtab[t1] = (9.0f * (1.0f - exp2f(m1 * L2A)) -
                4.0f * (1.0f - exp2f(m1 * L2D))) * (1.0f / (float)T);
  }
  __syncthreads();

  // ---------------- S6: LSNN scan, wave 0 only, from LDS
  if (tid < 64) {
    float gs = 0.f;
#pragma unroll
    for (int i = 0; i < 16; ++i) gs += gtab[lane + 64 * i];
    float gtot = __shfl(wred(gs), 0, 64);

    const int slot = lane < H ? lane : 0;   // inactive lanes broadcast slot 0
    float wr[H];
#pragma unroll
    for (int j = 0; j < H; ++j)
      wr[j] = (lane < H) ? p.W_rec[lane * H + j] : 0.f;

    float cur = 0.f, vm = 0.f, S = 0.f;
    unsigned zm = 0u;

    auto step = [&](float iin, float gt) {
      float p01 = (((zm >> 0) & 1u) ? wr[0] : 0.f) + (((zm >> 1) & 1u) ? wr[1] : 0.f);
      float p23 = (((zm >> 2) & 1u) ? wr[2] : 0.f) + (((zm >> 3) & 1u) ? wr[3] : 0.f);
      float p45 = (((zm >> 4) & 1u) ? wr[4] : 0.f) + (((zm >> 5) & 1u) ? wr[5] : 0.f);
      float p67 = (((zm >> 6) & 1u) ? wr[6] : 0.f) + (((zm >> 7) & 1u) ? wr[7] : 0.f);
      float p89 = (((zm >> 8) & 1u) ? wr[8] : 0.f) + (((zm >> 9) & 1u) ? wr[9] : 0.f);
      float rec = ((p01 + p23) + (p45 + p67)) + p89;
      float i_jump = (cur + iin) + rec;
      float v_dec = fmaf(0.1f, i_jump - vm, vm);  // vm + 0.1*(i_jump - vm)
      cur = 0.8f * i_jump;                        // i_dec
      bool z = v_dec > 0.5f;
      vm = z ? 0.f : v_dec;
      S += z ? gt : 0.f;
      zm = (unsigned)__ballot(z) & 0x3FFu;
    };

    float ibuf[8];
#pragma unroll
    for (int u = 0; u < 8; ++u) ibuf[u] = slab[u * 11 + slot];
    float4 gA = *(const float4*)&gtab[0], gB = *(const float4*)&gtab[4];

    for (int t8 = 0; t8 < T - 8; t8 += 8) {
      float4 nA = *(const float4*)&gtab[t8 + 8];
      float4 nB = *(const float4*)&gtab[t8 + 12];
      step(ibuf[0], gA.x); ibuf[0] = slab[(t8 +  8) * 11 + slot];
      step(ibuf[1], gA.y); ibuf[1] = slab[(t8 +  9) * 11 + slot];
      step(ibuf[2], gA.z); ibuf[2] = slab[(t8 + 10) * 11 + slot];
      step(ibuf[3], gA.w); ibuf[3] = slab[(t8 + 11) * 11 + slot];
      step(ibuf[4], gB.x); ibuf[4] = slab[(t8 + 12) * 11 + slot];
      step(ibuf[5], gB.y); ibuf[5] = slab[(t8 + 13) * 11 + slot];
      step(ibuf[6], gB.z); ibuf[6] = slab[(t8 + 14) * 11 + slot];
      step(ibuf[7], gB.w); ibuf[7] = slab[(t8 + 15) * 11 + slot];
      gA = nA; gB = nB;
    }
    step(ibuf[0], gA.x); step(ibuf[1], gA.y);
    step(ibuf[2], gA.z); step(ibuf[3], gA.w);
    step(ibuf[4], gB.x); step(ibuf[5], gB.y);
    step(ibuf[6], gB.z); step(ibuf[7], gB.w);

    int li = lane < H ? lane : 0;
    float c0 = (lane < H) ? S * p.W_cls[li]     : 0.f;
    float c1 = (lane < H) ? S * p.W_cls[H + li] : 0.f;
    float r0 = wred(c0), r1 = wred(c1);
    if (lane == 0) {
      p.out[b * 2 + 0] = r0 + gtot * p.b_cls[0];
      p.out[b * 2 + 1] = r1 + gtot * p.b_cls[1];
    }
  }
}

extern "C" void kernel_launch(void* const* d_in, const int* in_sizes, int n_in,
                              void* d_out, int out_size, void* d_ws, size_t ws_size,
                              hipStream_t stream) {
  Params p;
  p.beeg  = (const float*)d_in[2];
  p.W_ef  = (const float*)d_in[4];
  p.b_ef  = (const float*)d_in[5];
  p.g_i   = (const float*)d_in[6];
  p.be_i  = (const float*)d_in[7];
  p.Wq    = (const float*)d_in[8];
  p.g_q   = (const float*)d_in[9];
  p.be_q  = (const float*)d_in[10];
  p.Wk    = (const float*)d_in[11];
  p.g_k   = (const float*)d_in[12];
  p.be_k  = (const float*)d_in[13];
  p.Wv    = (const float*)d_in[14];
  p.g_v   = (const float*)d_in[15];
  p.be_v  = (const float*)d_in[16];
  p.Wc    = (const float*)d_in[17];
  p.g_c   = (const float*)d_in[18];
  p.be_c  = (const float*)d_in[19];
  p.W_in  = (const float*)d_in[20];
  p.W_rec = (const float*)d_in[21];
  p.W_cls = (const float*)d_in[22];
  p.b_cls = (const float*)d_in[23];

  char* ws = (char*)d_ws;
  p.cnt = (int*)ws;                            // 3 counters, memset below
  p.P1  = (double*)(ws + 256);                 // 32*20 doubles
  p.P2  = (double*)(ws + 256 + 5120);          // 32*60 doubles
  p.P3  = (double*)(ws + 256 + 5120 + 15360);  // 32*20 doubles
  p.out = (float*)d_out;

  hipMemsetAsync(d_ws, 0, 256, stream);   // zero barrier counters (capturable)
  fused6<<<dim3(B), dim3(NT), 0, stream>>>(p);
}

// Round 10
// 300.483 us; speedup vs baseline: 1.0095x; 1.0095x over previous
//
#include <hip/hip_runtime.h>
#include <math.h>

// Model: B=32, C=64, T=1024, H=10, OUT=2.
// ONE kernel, 32 blocks (one per batch element) x 512 threads; each thread
// owns TWO time-steps (t, t+512). S1 embed | S2 bn+tanh + qkv stats |
// S3 M=KV^T in TWO sequential passes | S4 N=M Wc^T/H, recompute q ->
// prec=q.N | S5 bn+relu -> Iin into LDS | S6 LSNN scan on wave 0.
//
// R9 post-mortem: spills gone (WRITE 8.2MB->877KB) but dur 203->199us.
// Accounting: stages ~15us + S1 HBM ~11us + scan ~30us => ~45us PER global
// barrier unexplained (matches R3's CG grid.sync ~35us). Suspect: gbar's
// __threadfence() (device-scope buffer_wbl2/inv = L2 writeback-invalidate)
// + ACQUIRE spin loads (L2 invalidate PER POLL x 32 spinners).
// R10: fence-free barrier. All cross-block data (P1/P2/P3, cnt) flow
// exclusively through AGENT-scope atomics (sc1 -> coherent point, bypassing
// the non-coherent XCD L2s); RELEASE on the counter increment orders the
// preceding partial stores via vmcnt(0). Spin is RELAXED (no invalidates).
// Plus: closed-form gtot, g-table built at staging time, W_rec/W_cls/b_cls
// pre-staged in LDS so the scan tail has no global-latency dependency.

constexpr int B = 32, C = 64, T = 1024, H = 10;
constexpr int NT = 512;   // threads per block (8 waves)

struct Params {
  const float *beeg, *W_ef, *b_ef, *g_i, *be_i, *Wq, *g_q, *be_q, *Wk, *g_k,
      *be_k, *Wv, *g_v, *be_v, *Wc, *g_c, *be_c, *W_in, *W_rec, *W_cls, *b_cls;
  int* cnt;              // barrier counters (memset 0 each launch)
  double *P1, *P2, *P3;  // cross-block stat partials
  float* out;
};

__device__ inline float wred(float v) {
#pragma unroll
  for (int o = 32; o; o >>= 1) v += __shfl_down(v, o, 64);
  return v;
}

// 32-block barrier, FENCE-FREE. Safe because every cross-block datum is
// read/written only via agent-scope atomics (which operate at the coherent
// point); RELEASE on the add orders the preceding partial stores (vmcnt).
__device__ inline void gbar(int* cnt, int phase, int tid) {
  __syncthreads();
  if (tid == 0) {
    __hip_atomic_fetch_add(&cnt[phase], 1, __ATOMIC_RELEASE,
                           __HIP_MEMORY_SCOPE_AGENT);
    while (__hip_atomic_load(&cnt[phase], __ATOMIC_RELAXED,
                             __HIP_MEMORY_SCOPE_AGENT) < B)
      __builtin_amdgcn_s_sleep(2);
  }
  __syncthreads();
}

// wlds layout (floats)
#define WEF 0      // 640: W_ef
#define WQ  640    // 100
#define WK  740    // 100
#define WV  840    // 100
#define WC  940    // 100
#define WIN 1040   // 100
#define GI  1140
#define BEI 1150
#define GQ  1160
#define BEQ 1170
#define GK  1180
#define BEK 1190
#define GV  1200
#define BEV 1210
#define GC  1220
#define BEC 1230
#define BEF 1240   // 10
#define WREC 1250  // 100: W_rec (for scan)
#define WCLS 1350  // 20: W_cls
#define BCLS 1370  // 2: b_cls

__global__ void __launch_bounds__(NT) fused7(Params p) {
  const int b = blockIdx.x, tid = threadIdx.x;
  const int lane = tid & 63, wid = tid >> 6;   // 8 waves
  const int t0 = tid, t1 = tid + NT;

  __shared__ __align__(16) float slab[T * 11];  // 45056 B: scratch then Iin
  __shared__ __align__(16) float gtab[T];       // 4 KB
  __shared__ float wlds[1372 + 4];              // staged weights/params
  __shared__ double dtot[60];
  __shared__ float stM[30], stI[30], Ms[100], Nl[100];

  float* swred = slab;         // [8][60] stats scratch (dead before S5)
  float* mpw   = slab + 512;   // [8][100] M partials (dead before S5)

  // ---------------- stage all small weights into LDS + g-table
  for (int i = tid; i < 640; i += NT) wlds[WEF + i] = p.W_ef[i];
  if (tid < 100) {
    wlds[WQ + tid]   = p.Wq[tid];
    wlds[WK + tid]   = p.Wk[tid];
    wlds[WV + tid]   = p.Wv[tid];
    wlds[WC + tid]   = p.Wc[tid];
    wlds[WIN + tid]  = p.W_in[tid];
    wlds[WREC + tid] = p.W_rec[tid];
  }
  if (tid < 20) wlds[WCLS + tid] = p.W_cls[tid];
  if (tid < 10) {
    wlds[GI + tid]  = p.g_i[tid];  wlds[BEI + tid] = p.be_i[tid];
    wlds[GQ + tid]  = p.g_q[tid];  wlds[BEQ + tid] = p.be_q[tid];
    wlds[GK + tid]  = p.g_k[tid];  wlds[BEK + tid] = p.be_k[tid];
    wlds[GV + tid]  = p.g_v[tid];  wlds[BEV + tid] = p.be_v[tid];
    wlds[GC + tid]  = p.g_c[tid];  wlds[BEC + tid] = p.be_c[tid];
    wlds[BEF + tid] = p.b_ef[tid];
  }
  if (tid < 2) wlds[BCLS + tid] = p.b_cls[tid];
  {
    // g[t] = (9(1-0.9^{T-t}) - 4(1-0.8^{T-t})) / T
    const float L2A = -0.15200309344504995f;   // log2(0.9)
    const float L2D = -0.32192809488736235f;   // log2(0.8)
    float m0 = (float)(T - t0), m1 = (float)(T - t1);
    gtab[t0] = (9.0f * (1.0f - exp2f(m0 * L2A)) -
                4.0f * (1.0f - exp2f(m0 * L2D))) * (1.0f / (float)T);
    gtab[t1] = (9.0f * (1.0f - exp2f(m1 * L2A)) -
                4.0f * (1.0f - exp2f(m1 * L2D))) * (1.0f / (float)T);
  }
  __syncthreads();

  // ---------------- S1: embed (two t's per thread)
  float p1a[H], p1b[H];
#pragma unroll
  for (int h = 0; h < H; ++h) { p1a[h] = wlds[BEF + h]; p1b[h] = wlds[BEF + h]; }
  {
    const float* bp = p.beeg + (size_t)b * C * T;
    for (int c = 0; c < C; ++c) {
      float va = bp[(size_t)c * T + t0];
      float vb = bp[(size_t)c * T + t1];
#pragma unroll
      for (int h = 0; h < H; ++h) {
        float w = wlds[WEF + h * C + c];
        p1a[h] = fmaf(va, w, p1a[h]);
        p1b[h] = fmaf(vb, w, p1b[h]);
      }
    }
  }
#pragma unroll
  for (int h = 0; h < H; ++h) {
    float r1 = wred(p1a[h] + p1b[h]);
    float r2 = wred(p1a[h] * p1a[h] + p1b[h] * p1b[h]);
    if (lane == 0) { swred[wid * 60 + h] = r1; swred[wid * 60 + 10 + h] = r2; }
  }
  __syncthreads();
  if (tid < 20) {
    double s = 0.0;
#pragma unroll
    for (int w = 0; w < 8; ++w) s += (double)swred[w * 60 + tid];
    __hip_atomic_store(&p.P1[b * 20 + tid], s, __ATOMIC_RELAXED,
                       __HIP_MEMORY_SCOPE_AGENT);
  }
  gbar(p.cnt, 0, tid);
  if (tid < 20) {
    double s = 0.0;
    for (int i = 0; i < B; ++i)
      s += __hip_atomic_load(&p.P1[i * 20 + tid], __ATOMIC_RELAXED,
                             __HIP_MEMORY_SCOPE_AGENT);
    dtot[tid] = s;
  }
  __syncthreads();
  if (tid < 10) {
    double mean = dtot[tid] * (1.0 / 32768.0);
    double var  = dtot[10 + tid] * (1.0 / 32768.0) - mean * mean;
    stM[tid] = (float)mean;
    stI[tid] = (float)(1.0 / sqrt(var + 1e-5));
  }
  __syncthreads();

  // ---------------- S2: x = tanh(bn(pre1)); qkv stats (accumulators only)
  float xa[H], xb[H];
#pragma unroll
  for (int j = 0; j < H; ++j) {
    xa[j] = tanhf(wlds[GI + j] * (p1a[j] - stM[j]) * stI[j] + wlds[BEI + j]);
    xb[j] = tanhf(wlds[GI + j] * (p1b[j] - stM[j]) * stI[j] + wlds[BEI + j]);
  }
  // p1a/p1b dead; only xa/xb (20 floats) persist from here on.
#pragma unroll
  for (int h = 0; h < H; ++h) {
    float qa = 0.f, qb = 0.f, ka = 0.f, kb = 0.f, va = 0.f, vb = 0.f;
#pragma unroll
    for (int j = 0; j < H; ++j) {
      float wq = wlds[WQ + h * H + j], wk = wlds[WK + h * H + j],
            wv = wlds[WV + h * H + j];
      qa = fmaf(xa[j], wq, qa); qb = fmaf(xb[j], wq, qb);
      ka = fmaf(xa[j], wk, ka); kb = fmaf(xb[j], wk, kb);
      va = fmaf(xa[j], wv, va); vb = fmaf(xb[j], wv, vb);
    }
    float r1 = wred(qa + qb), r2 = wred(qa * qa + qb * qb);
    float r3 = wred(ka + kb), r4 = wred(ka * ka + kb * kb);
    float r5 = wred(va + vb), r6 = wred(va * va + vb * vb);
    if (lane == 0) {
      swred[wid * 60 + h]      = r1; swred[wid * 60 + 30 + h] = r2;
      swred[wid * 60 + 10 + h] = r3; swred[wid * 60 + 40 + h] = r4;
      swred[wid * 60 + 20 + h] = r5; swred[wid * 60 + 50 + h] = r6;
    }
  }
  __syncthreads();
  if (tid < 60) {
    double s = 0.0;
#pragma unroll
    for (int w = 0; w < 8; ++w) s += (double)swred[w * 60 + tid];
    __hip_atomic_store(&p.P2[b * 60 + tid], s, __ATOMIC_RELAXED,
                       __HIP_MEMORY_SCOPE_AGENT);
  }
  gbar(p.cnt, 1, tid);
  if (tid < 60) {
    double s = 0.0;
    for (int i = 0; i < B; ++i)
      s += __hip_atomic_load(&p.P2[i * 60 + tid], __ATOMIC_RELAXED,
                             __HIP_MEMORY_SCOPE_AGENT);
    dtot[tid] = s;
  }
  __syncthreads();
  if (tid < 30) {
    double mean = dtot[tid] * (1.0 / 32768.0);
    double var  = dtot[30 + tid] * (1.0 / 32768.0) - mean * mean;
    stM[tid] = (float)mean;
    stI[tid] = (float)(1.0 / sqrt(var + 1e-5));
  }
  __syncthreads();

  // ---------------- S3: M = KV^T in two sequential passes (low pressure)
  {  // pass a
    float kx[H], vx[H];
#pragma unroll
    for (int h = 0; h < H; ++h) {
      float ka = 0.f, va = 0.f;
#pragma unroll
      for (int j = 0; j < H; ++j) {
        ka = fmaf(xa[j], wlds[WK + h * H + j], ka);
        va = fmaf(xa[j], wlds[WV + h * H + j], va);
      }
      kx[h] = fmaxf(wlds[GK + h] * (ka - stM[10 + h]) * stI[10 + h] + wlds[BEK + h], 0.f);
      vx[h] = tanhf(wlds[GV + h] * (va - stM[20 + h]) * stI[20 + h] + wlds[BEV + h]);
    }
#pragma unroll
    for (int i = 0; i < H; ++i)
#pragma unroll
      for (int j = 0; j < H; ++j) {
        float r = wred(kx[i] * vx[j]);
        if (lane == 0) mpw[wid * 100 + i * 10 + j] = r;
      }
  }
  {  // pass b (accumulate)
    float kx[H], vx[H];
#pragma unroll
    for (int h = 0; h < H; ++h) {
      float kb = 0.f, vb = 0.f;
#pragma unroll
      for (int j = 0; j < H; ++j) {
        kb = fmaf(xb[j], wlds[WK + h * H + j], kb);
        vb = fmaf(xb[j], wlds[WV + h * H + j], vb);
      }
      kx[h] = fmaxf(wlds[GK + h] * (kb - stM[10 + h]) * stI[10 + h] + wlds[BEK + h], 0.f);
      vx[h] = tanhf(wlds[GV + h] * (vb - stM[20 + h]) * stI[20 + h] + wlds[BEV + h]);
    }
#pragma unroll
    for (int i = 0; i < H; ++i)
#pragma unroll
      for (int j = 0; j < H; ++j) {
        float r = wred(kx[i] * vx[j]);
        if (lane == 0) mpw[wid * 100 + i * 10 + j] += r;
      }
  }
  __syncthreads();
  if (tid < 100) {
    float s = 0.f;
#pragma unroll
    for (int w = 0; w < 8; ++w) s += mpw[w * 100 + tid];
    Ms[tid] = s;
  }
  __syncthreads();

  // ---------------- S4: N = (M Wc^T)/H; recompute q; prec = q . N
  if (tid < 100) {
    int i = tid / 10, h = tid % 10;
    float a = 0.f;
#pragma unroll
    for (int j = 0; j < H; ++j) a = fmaf(Ms[i * 10 + j], wlds[WC + h * H + j], a);
    Nl[tid] = a * 0.1f;
  }
  __syncthreads();
  float pca[H], pcb[H];
  {  // pass a
    float qv[H];
#pragma unroll
    for (int h = 0; h < H; ++h) {
      float qa = 0.f;
#pragma unroll
      for (int j = 0; j < H; ++j) qa = fmaf(xa[j], wlds[WQ + h * H + j], qa);
      qv[h] = fmaxf(wlds[GQ + h] * (qa - stM[h]) * stI[h] + wlds[BEQ + h], 0.f);
    }
#pragma unroll
    for (int h = 0; h < H; ++h) {
      float a = 0.f;
#pragma unroll
      for (int i = 0; i < H; ++i) a = fmaf(qv[i], Nl[i * 10 + h], a);
      pca[h] = a;
    }
  }
  {  // pass b
    float qv[H];
#pragma unroll
    for (int h = 0; h < H; ++h) {
      float qb = 0.f;
#pragma unroll
      for (int j = 0; j < H; ++j) qb = fmaf(xb[j], wlds[WQ + h * H + j], qb);
      qv[h] = fmaxf(wlds[GQ + h] * (qb - stM[h]) * stI[h] + wlds[BEQ + h], 0.f);
    }
#pragma unroll
    for (int h = 0; h < H; ++h) {
      float a = 0.f;
#pragma unroll
      for (int i = 0; i < H; ++i) a = fmaf(qv[i], Nl[i * 10 + h], a);
      pcb[h] = a;
    }
  }
  // xa/xb dead now; pca/pcb (20 floats) live.
#pragma unroll
  for (int h = 0; h < H; ++h) {
    float r1 = wred(pca[h] + pcb[h]);
    float r2 = wred(pca[h] * pca[h] + pcb[h] * pcb[h]);
    if (lane == 0) { swred[wid * 60 + h] = r1; swred[wid * 60 + 10 + h] = r2; }
  }
  __syncthreads();
  if (tid < 20) {
    double s = 0.0;
#pragma unroll
    for (int w = 0; w < 8; ++w) s += (double)swred[w * 60 + tid];
    __hip_atomic_store(&p.P3[b * 20 + tid], s, __ATOMIC_RELAXED,
                       __HIP_MEMORY_SCOPE_AGENT);
  }
  gbar(p.cnt, 2, tid);
  if (tid < 20) {
    double s = 0.0;
    for (int i = 0; i < B; ++i)
      s += __hip_atomic_load(&p.P3[i * 20 + tid], __ATOMIC_RELAXED,
                             __HIP_MEMORY_SCOPE_AGENT);
    dtot[tid] = s;
  }
  __syncthreads();
  if (tid < 10) {
    double mean = dtot[tid] * (1.0 / 32768.0);
    double var  = dtot[10 + tid] * (1.0 / 32768.0) - mean * mean;
    stM[tid] = (float)mean;
    stI[tid] = (float)(1.0 / sqrt(var + 1e-5));
  }
  __syncthreads();   // all slab-scratch reads done before S5 overwrites

  // ---------------- S5: bn+relu, Iin into LDS slab (stride 11)
  {
    float ca[H];
#pragma unroll
    for (int j = 0; j < H; ++j)
      ca[j] = fmaxf(wlds[GC + j] * (pca[j] - stM[j]) * stI[j] + wlds[BEC + j], 0.f);
#pragma unroll
    for (int h = 0; h < H; ++h) {
      float a = 0.f;
#pragma unroll
      for (int j = 0; j < H; ++j) a = fmaf(ca[j], wlds[WIN + h * H + j], a);
      slab[t0 * 11 + h] = a;
    }
#pragma unroll
    for (int j = 0; j < H; ++j)
      ca[j] = fmaxf(wlds[GC + j] * (pcb[j] - stM[j]) * stI[j] + wlds[BEC + j], 0.f);
#pragma unroll
    for (int h = 0; h < H; ++h) {
      float a = 0.f;
#pragma unroll
      for (int j = 0; j < H; ++j) a = fmaf(ca[j], wlds[WIN + h * H + j], a);
      slab[t1 * 11 + h] = a;
    }
  }
  __syncthreads();

  // ---------------- S6: LSNN scan, wave 0 only, from LDS
  if (tid < 64) {
    // gtot = sum_t g_t, closed form: (9T - 81(1-.9^T) - 4T + 16(1-.8^T))/T;
    // .9^1024 and .8^1024 underflow f32 -> (5*1024 - 81 + 16)/1024.
    const float gtot = 4.9365234375f;

    const int slot = lane < H ? lane : 0;   // inactive lanes broadcast slot 0
    float wr[H];
#pragma unroll
    for (int j = 0; j < H; ++j)
      wr[j] = (lane < H) ? wlds[WREC + lane * H + j] : 0.f;

    float cur = 0.f, vm = 0.f, S = 0.f;
    unsigned zm = 0u;

    auto step = [&](float iin, float gt) {
      float p01 = (((zm >> 0) & 1u) ? wr[0] : 0.f) + (((zm >> 1) & 1u) ? wr[1] : 0.f);
      float p23 = (((zm >> 2) & 1u) ? wr[2] : 0.f) + (((zm >> 3) & 1u) ? wr[3] : 0.f);
      float p45 = (((zm >> 4) & 1u) ? wr[4] : 0.f) + (((zm >> 5) & 1u) ? wr[5] : 0.f);
      float p67 = (((zm >> 6) & 1u) ? wr[6] : 0.f) + (((zm >> 7) & 1u) ? wr[7] : 0.f);
      float p89 = (((zm >> 8) & 1u) ? wr[8] : 0.f) + (((zm >> 9) & 1u) ? wr[9] : 0.f);
      float rec = ((p01 + p23) + (p45 + p67)) + p89;
      float i_jump = (cur + iin) + rec;
      float v_dec = fmaf(0.1f, i_jump - vm, vm);  // vm + 0.1*(i_jump - vm)
      cur = 0.8f * i_jump;                        // i_dec
      bool z = v_dec > 0.5f;
      vm = z ? 0.f : v_dec;
      S += z ? gt : 0.f;
      zm = (unsigned)__ballot(z) & 0x3FFu;
    };

    float ibuf[8];
#pragma unroll
    for (int u = 0; u < 8; ++u) ibuf[u] = slab[u * 11 + slot];
    float4 gA = *(const float4*)&gtab[0], gB = *(const float4*)&gtab[4];

    for (int t8 = 0; t8 < T - 8; t8 += 8) {
      float4 nA = *(const float4*)&gtab[t8 + 8];
      float4 nB = *(const float4*)&gtab[t8 + 12];
      step(ibuf[0], gA.x); ibuf[0] = slab[(t8 +  8) * 11 + slot];
      step(ibuf[1], gA.y); ibuf[1] = slab[(t8 +  9) * 11 + slot];
      step(ibuf[2], gA.z); ibuf[2] = slab[(t8 + 10) * 11 + slot];
      step(ibuf[3], gA.w); ibuf[3] = slab[(t8 + 11) * 11 + slot];
      step(ibuf[4], gB.x); ibuf[4] = slab[(t8 + 12) * 11 + slot];
      step(ibuf[5], gB.y); ibuf[5] = slab[(t8 + 13) * 11 + slot];
      step(ibuf[6], gB.z); ibuf[6] = slab[(t8 + 14) * 11 + slot];
      step(ibuf[7], gB.w); ibuf[7] = slab[(t8 + 15) * 11 + slot];
      gA = nA; gB = nB;
    }
    step(ibuf[0], gA.x); step(ibuf[1], gA.y);
    step(ibuf[2], gA.z); step(ibuf[3], gA.w);
    step(ibuf[4], gB.x); step(ibuf[5], gB.y);
    step(ibuf[6], gB.z); step(ibuf[7], gB.w);

    int li = lane < H ? lane : 0;
    float c0 = (lane < H) ? S * wlds[WCLS + li]     : 0.f;
    float c1 = (lane < H) ? S * wlds[WCLS + H + li] : 0.f;
    float r0 = wred(c0), r1 = wred(c1);
    if (lane == 0) {
      p.out[b * 2 + 0] = r0 + gtot * wlds[BCLS + 0];
      p.out[b * 2 + 1] = r1 + gtot * wlds[BCLS + 1];
    }
  }
}

extern "C" void kernel_launch(void* const* d_in, const int* in_sizes, int n_in,
                              void* d_out, int out_size, void* d_ws, size_t ws_size,
                              hipStream_t stream) {
  Params p;
  p.beeg  = (const float*)d_in[2];
  p.W_ef  = (const float*)d_in[4];
  p.b_ef  = (const float*)d_in[5];
  p.g_i   = (const float*)d_in[6];
  p.be_i  = (const float*)d_in[7];
  p.Wq    = (const float*)d_in[8];
  p.g_q   = (const float*)d_in[9];
  p.be_q  = (const float*)d_in[10];
  p.Wk    = (const float*)d_in[11];
  p.g_k   = (const float*)d_in[12];
  p.be_k  = (const float*)d_in[13];
  p.Wv    = (const float*)d_in[14];
  p.g_v   = (const float*)d_in[15];
  p.be_v  = (const float*)d_in[16];
  p.Wc    = (const float*)d_in[17];
  p.g_c   = (const float*)d_in[18];
  p.be_c  = (const float*)d_in[19];
  p.W_in  = (const float*)d_in[20];
  p.W_rec = (const float*)d_in[21];
  p.W_cls = (const float*)d_in[22];
  p.b_cls = (const float*)d_in[23];

  char* ws = (char*)d_ws;
  p.cnt = (int*)ws;                            // 3 counters, memset below
  p.P1  = (double*)(ws + 256);                 // 32*20 doubles
  p.P2  = (double*)(ws + 256 + 5120);          // 32*60 doubles
  p.P3  = (double*)(ws + 256 + 5120 + 15360);  // 32*20 doubles
  p.out = (float*)d_out;

  hipMemsetAsync(d_ws, 0, 256, stream);   // zero barrier counters (capturable)
  fused7<<<dim3(B), dim3(NT), 0, stream>>>(p);
}

// Round 12
// 267.856 us; speedup vs baseline: 1.1324x; 1.1218x over previous
//
#include <hip/hip_runtime.h>
#include <math.h>

// Model: B=32, C=64, T=1024, H=10, OUT=2.
// ONE kernel, 32 blocks (one per batch element) x 512 threads; each thread
// owns TWO time-steps (t, t+512). S1 embed | S2 bn+tanh + qkv stats |
// S3 M=KV^T two passes | S4 N=M Wc^T/H, recompute q -> prec=q.N |
// S5 bn+relu -> Iin into LDS | S6 LSNN scan on wave 0 from LDS.
//
// R10 post-mortem: fence-free barrier changed nothing (196us) -- the stall
// is LDS-PIPE SERIALIZATION: ~4500 DS inst/wave (weight ds_reads + shfl
// ds_swizzles) x 8 waves x ~5.8cyc ~= 87us on one LDS pipe/CU.
// R11/R12: (1) weights read from GLOBAL with wave-uniform indices ->
// compiler scalarizes to s_load/SGPR (K$, scalar pipe, zero LDS+VALU cost);
// (2) wave reductions via DPP (row_shr/row_bcast, VALU pipe, lane 63)
// instead of __shfl_down (DS pipe). R12 fixes R11's compile error: DPP
// ctrl must be a compile-time constant -> template parameter.
// Slab padded +8KB so occupancy-by-LDS still yields the 128-VGPR budget
// (R8 lesson: budget = 512 / (waves from LDS-derived occupancy)).

constexpr int B = 32, C = 64, T = 1024, H = 10;
constexpr int NT = 512;   // threads per block (8 waves)

struct Params {
  const float *beeg, *W_ef, *b_ef, *g_i, *be_i, *Wq, *g_q, *be_q, *Wk, *g_k,
      *be_k, *Wv, *g_v, *be_v, *Wc, *g_c, *be_c, *W_in, *W_rec, *W_cls, *b_cls;
  int* cnt;              // barrier counters (memset 0 each launch)
  double *P1, *P2, *P3;  // cross-block stat partials
  float* out;
};

// DPP wave64 sum: result valid in lane 63 (VALU pipe, no DS traffic).
template <int CTRL>
__device__ inline float dadd(float v) {
  int x = __builtin_amdgcn_update_dpp(0, __float_as_int(v), CTRL, 0xf, 0xf,
                                      true);
  return v + __int_as_float(x);
}
__device__ inline float wred63(float v) {
  v = dadd<0x111>(v);  // row_shr:1
  v = dadd<0x112>(v);  // row_shr:2
  v = dadd<0x114>(v);  // row_shr:4
  v = dadd<0x118>(v);  // row_shr:8
  v = dadd<0x142>(v);  // row_bcast:15
  v = dadd<0x143>(v);  // row_bcast:31
  return v;            // lane 63 = full sum
}

// 32-block barrier, fence-free (all cross-block data via agent-scope atomics).
__device__ inline void gbar(int* cnt, int phase, int tid) {
  __syncthreads();
  if (tid == 0) {
    __hip_atomic_fetch_add(&cnt[phase], 1, __ATOMIC_RELEASE,
                           __HIP_MEMORY_SCOPE_AGENT);
    while (__hip_atomic_load(&cnt[phase], __ATOMIC_RELAXED,
                             __HIP_MEMORY_SCOPE_AGENT) < B)
      __builtin_amdgcn_s_sleep(2);
  }
  __syncthreads();
}

__global__ void __launch_bounds__(NT) fused9(Params p) {
  const int b = blockIdx.x, tid = threadIdx.x;
  const int lane = tid & 63, wid = tid >> 6;   // 8 waves
  const int t0 = tid, t1 = tid + NT;

  // slab: scratch (stats/M partials) then Iin[t][h] stride 11.
  // +2048 floats pad => LDS ~57.5KB => 2 WGs/CU by the occupancy heuristic
  // => 4 waves/EU => 128-VGPR budget (keeps the no-spill regime of R8/R9).
  __shared__ __align__(16) float slab[T * 11 + 2048];
  __shared__ __align__(16) float gtab[T];
  __shared__ double dtot[60];
  __shared__ float stM[30], stI[30], Ms[100], Nl[100];

  float* swred = slab;         // [8][60] stats scratch (dead before S5)
  float* mpw   = slab + 512;   // [8][100] M partials (dead before S5)

  // g[t] = (9(1-0.9^{T-t}) - 4(1-0.8^{T-t})) / T  (f32 closed form)
  {
    const float L2A = -0.15200309344504995f;   // log2(0.9)
    const float L2D = -0.32192809488736235f;   // log2(0.8)
    float m0 = (float)(T - t0), m1 = (float)(T - t1);
    gtab[t0] = (9.0f * (1.0f - exp2f(m0 * L2A)) -
                4.0f * (1.0f - exp2f(m0 * L2D))) * (1.0f / (float)T);
    gtab[t1] = (9.0f * (1.0f - exp2f(m1 * L2A)) -
                4.0f * (1.0f - exp2f(m1 * L2D))) * (1.0f / (float)T);
  }

  // ---------------- S1: embed (weights via uniform/scalar loads)
  float p1a[H], p1b[H];
#pragma unroll
  for (int h = 0; h < H; ++h) { p1a[h] = p.b_ef[h]; p1b[h] = p.b_ef[h]; }
  {
    const float* bp = p.beeg + (size_t)b * C * T;
    for (int c = 0; c < C; ++c) {
      float va = bp[(size_t)c * T + t0];
      float vb = bp[(size_t)c * T + t1];
#pragma unroll
      for (int h = 0; h < H; ++h) {
        float w = p.W_ef[h * C + c];   // wave-uniform -> s_load
        p1a[h] = fmaf(va, w, p1a[h]);
        p1b[h] = fmaf(vb, w, p1b[h]);
      }
    }
  }
#pragma unroll
  for (int h = 0; h < H; ++h) {
    float r1 = wred63(p1a[h] + p1b[h]);
    float r2 = wred63(p1a[h] * p1a[h] + p1b[h] * p1b[h]);
    if (lane == 63) { swred[wid * 60 + h] = r1; swred[wid * 60 + 10 + h] = r2; }
  }
  __syncthreads();
  if (tid < 20) {
    double s = 0.0;
#pragma unroll
    for (int w = 0; w < 8; ++w) s += (double)swred[w * 60 + tid];
    __hip_atomic_store(&p.P1[b * 20 + tid], s, __ATOMIC_RELAXED,
                       __HIP_MEMORY_SCOPE_AGENT);
  }
  gbar(p.cnt, 0, tid);
  if (tid < 20) {
    double s = 0.0;
    for (int i = 0; i < B; ++i)
      s += __hip_atomic_load(&p.P1[i * 20 + tid], __ATOMIC_RELAXED,
                             __HIP_MEMORY_SCOPE_AGENT);
    dtot[tid] = s;
  }
  __syncthreads();
  if (tid < 10) {
    double mean = dtot[tid] * (1.0 / 32768.0);
    double var  = dtot[10 + tid] * (1.0 / 32768.0) - mean * mean;
    stM[tid] = (float)mean;
    stI[tid] = (float)(1.0 / sqrt(var + 1e-5));
  }
  __syncthreads();

  // ---------------- S2: x = tanh(bn(pre1)); qkv stats (accumulators only)
  float xa[H], xb[H];
#pragma unroll
  for (int j = 0; j < H; ++j) {
    xa[j] = tanhf(p.g_i[j] * (p1a[j] - stM[j]) * stI[j] + p.be_i[j]);
    xb[j] = tanhf(p.g_i[j] * (p1b[j] - stM[j]) * stI[j] + p.be_i[j]);
  }
  // p1a/p1b dead; only xa/xb (20 floats) persist from here on.
#pragma unroll
  for (int h = 0; h < H; ++h) {
    float qa = 0.f, qb = 0.f, ka = 0.f, kb = 0.f, va = 0.f, vb = 0.f;
#pragma unroll
    for (int j = 0; j < H; ++j) {
      float wq = p.Wq[h * H + j], wk = p.Wk[h * H + j], wv = p.Wv[h * H + j];
      qa = fmaf(xa[j], wq, qa); qb = fmaf(xb[j], wq, qb);
      ka = fmaf(xa[j], wk, ka); kb = fmaf(xb[j], wk, kb);
      va = fmaf(xa[j], wv, va); vb = fmaf(xb[j], wv, vb);
    }
    float r1 = wred63(qa + qb), r2 = wred63(qa * qa + qb * qb);
    float r3 = wred63(ka + kb), r4 = wred63(ka * ka + kb * kb);
    float r5 = wred63(va + vb), r6 = wred63(va * va + vb * vb);
    if (lane == 63) {
      swred[wid * 60 + h]      = r1; swred[wid * 60 + 30 + h] = r2;
      swred[wid * 60 + 10 + h] = r3; swred[wid * 60 + 40 + h] = r4;
      swred[wid * 60 + 20 + h] = r5; swred[wid * 60 + 50 + h] = r6;
    }
  }
  __syncthreads();
  if (tid < 60) {
    double s = 0.0;
#pragma unroll
    for (int w = 0; w < 8; ++w) s += (double)swred[w * 60 + tid];
    __hip_atomic_store(&p.P2[b * 60 + tid], s, __ATOMIC_RELAXED,
                       __HIP_MEMORY_SCOPE_AGENT);
  }
  gbar(p.cnt, 1, tid);
  if (tid < 60) {
    double s = 0.0;
    for (int i = 0; i < B; ++i)
      s += __hip_atomic_load(&p.P2[i * 60 + tid], __ATOMIC_RELAXED,
                             __HIP_MEMORY_SCOPE_AGENT);
    dtot[tid] = s;
  }
  __syncthreads();
  if (tid < 30) {
    double mean = dtot[tid] * (1.0 / 32768.0);
    double var  = dtot[30 + tid] * (1.0 / 32768.0) - mean * mean;
    stM[tid] = (float)mean;
    stI[tid] = (float)(1.0 / sqrt(var + 1e-5));
  }
  __syncthreads();

  // ---------------- S3: M = KV^T in two sequential passes (low pressure)
  {  // pass a
    float kx[H], vx[H];
#pragma unroll
    for (int h = 0; h < H; ++h) {
      float ka = 0.f, va = 0.f;
#pragma unroll
      for (int j = 0; j < H; ++j) {
        ka = fmaf(xa[j], p.Wk[h * H + j], ka);
        va = fmaf(xa[j], p.Wv[h * H + j], va);
      }
      kx[h] = fmaxf(p.g_k[h] * (ka - stM[10 + h]) * stI[10 + h] + p.be_k[h], 0.f);
      vx[h] = tanhf(p.g_v[h] * (va - stM[20 + h]) * stI[20 + h] + p.be_v[h]);
    }
#pragma unroll
    for (int i = 0; i < H; ++i)
#pragma unroll
      for (int j = 0; j < H; ++j) {
        float r = wred63(kx[i] * vx[j]);
        if (lane == 63) mpw[wid * 100 + i * 10 + j] = r;
      }
  }
  {  // pass b (accumulate)
    float kx[H], vx[H];
#pragma unroll
    for (int h = 0; h < H; ++h) {
      float kb = 0.f, vb = 0.f;
#pragma unroll
      for (int j = 0; j < H; ++j) {
        kb = fmaf(xb[j], p.Wk[h * H + j], kb);
        vb = fmaf(xb[j], p.Wv[h * H + j], vb);
      }
      kx[h] = fmaxf(p.g_k[h] * (kb - stM[10 + h]) * stI[10 + h] + p.be_k[h], 0.f);
      vx[h] = tanhf(p.g_v[h] * (vb - stM[20 + h]) * stI[20 + h] + p.be_v[h]);
    }
#pragma unroll
    for (int i = 0; i < H; ++i)
#pragma unroll
      for (int j = 0; j < H; ++j) {
        float r = wred63(kx[i] * vx[j]);
        if (lane == 63) mpw[wid * 100 + i * 10 + j] += r;
      }
  }
  __syncthreads();
  if (tid < 100) {
    float s = 0.f;
#pragma unroll
    for (int w = 0; w < 8; ++w) s += mpw[w * 100 + tid];
    Ms[tid] = s;
  }
  __syncthreads();

  // ---------------- S4: N = (M Wc^T)/H; recompute q; prec = q . N
  if (tid < 100) {
    int i = tid / 10, h = tid % 10;
    float a = 0.f;
#pragma unroll
    for (int j = 0; j < H; ++j) a = fmaf(Ms[i * 10 + j], p.Wc[h * H + j], a);
    Nl[tid] = a * 0.1f;
  }
  __syncthreads();
  float pca[H], pcb[H];
  {  // pass a
    float qv[H];
#pragma unroll
    for (int h = 0; h < H; ++h) {
      float qa = 0.f;
#pragma unroll
      for (int j = 0; j < H; ++j) qa = fmaf(xa[j], p.Wq[h * H + j], qa);
      qv[h] = fmaxf(p.g_q[h] * (qa - stM[h]) * stI[h] + p.be_q[h], 0.f);
    }
#pragma unroll
    for (int h = 0; h < H; ++h) {
      float a = 0.f;
#pragma unroll
      for (int i = 0; i < H; ++i) a = fmaf(qv[i], Nl[i * 10 + h], a);
      pca[h] = a;
    }
  }
  {  // pass b
    float qv[H];
#pragma unroll
    for (int h = 0; h < H; ++h) {
      float qb = 0.f;
#pragma unroll
      for (int j = 0; j < H; ++j) qb = fmaf(xb[j], p.Wq[h * H + j], qb);
      qv[h] = fmaxf(p.g_q[h] * (qb - stM[h]) * stI[h] + p.be_q[h], 0.f);
    }
#pragma unroll
    for (int h = 0; h < H; ++h) {
      float a = 0.f;
#pragma unroll
      for (int i = 0; i < H; ++i) a = fmaf(qv[i], Nl[i * 10 + h], a);
      pcb[h] = a;
    }
  }
  // xa/xb dead now; pca/pcb (20 floats) live.
#pragma unroll
  for (int h = 0; h < H; ++h) {
    float r1 = wred63(pca[h] + pcb[h]);
    float r2 = wred63(pca[h] * pca[h] + pcb[h] * pcb[h]);
    if (lane == 63) { swred[wid * 60 + h] = r1; swred[wid * 60 + 10 + h] = r2; }
  }
  __syncthreads();
  if (tid < 20) {
    double s = 0.0;
#pragma unroll
    for (int w = 0; w < 8; ++w) s += (double)swred[w * 60 + tid];
    __hip_atomic_store(&p.P3[b * 20 + tid], s, __ATOMIC_RELAXED,
                       __HIP_MEMORY_SCOPE_AGENT);
  }
  gbar(p.cnt, 2, tid);
  if (tid < 20) {
    double s = 0.0;
    for (int i = 0; i < B; ++i)
      s += __hip_atomic_load(&p.P3[i * 20 + tid], __ATOMIC_RELAXED,
                             __HIP_MEMORY_SCOPE_AGENT);
    dtot[tid] = s;
  }
  __syncthreads();
  if (tid < 10) {
    double mean = dtot[tid] * (1.0 / 32768.0);
    double var  = dtot[10 + tid] * (1.0 / 32768.0) - mean * mean;
    stM[tid] = (float)mean;
    stI[tid] = (float)(1.0 / sqrt(var + 1e-5));
  }
  __syncthreads();   // all slab-scratch reads done before S5 overwrites

  // ---------------- S5: bn+relu, Iin into LDS slab (stride 11)
  {
    float ca[H];
#pragma unroll
    for (int j = 0; j < H; ++j)
      ca[j] = fmaxf(p.g_c[j] * (pca[j] - stM[j]) * stI[j] + p.be_c[j], 0.f);
#pragma unroll
    for (int h = 0; h < H; ++h) {
      float a = 0.f;
#pragma unroll
      for (int j = 0; j < H; ++j) a = fmaf(ca[j], p.W_in[h * H + j], a);
      slab[t0 * 11 + h] = a;
    }
#pragma unroll
    for (int j = 0; j < H; ++j)
      ca[j] = fmaxf(p.g_c[j] * (pcb[j] - stM[j]) * stI[j] + p.be_c[j], 0.f);
#pragma unroll
    for (int h = 0; h < H; ++h) {
      float a = 0.f;
#pragma unroll
      for (int j = 0; j < H; ++j) a = fmaf(ca[j], p.W_in[h * H + j], a);
      slab[t1 * 11 + h] = a;
    }
  }
  __syncthreads();

  // ---------------- S6: LSNN scan, wave 0 only, from LDS
  if (tid < 64) {
    // gtot closed form: .9^1024/.8^1024 underflow -> (5*1024 - 81 + 16)/1024
    const float gtot = 4.9365234375f;

    const int slot = lane < H ? lane : 0;   // inactive lanes broadcast slot 0
    float wr[H];
#pragma unroll
    for (int j = 0; j < H; ++j)
      wr[j] = (lane < H) ? p.W_rec[lane * H + j] : 0.f;  // one-time global

    float cur = 0.f, vm = 0.f, S = 0.f;
    unsigned zm = 0u;

    auto step = [&](float iin, float gt) {
      float p01 = (((zm >> 0) & 1u) ? wr[0] : 0.f) + (((zm >> 1) & 1u) ? wr[1] : 0.f);
      float p23 = (((zm >> 2) & 1u) ? wr[2] : 0.f) + (((zm >> 3) & 1u) ? wr[3] : 0.f);
      float p45 = (((zm >> 4) & 1u) ? wr[4] : 0.f) + (((zm >> 5) & 1u) ? wr[5] : 0.f);
      float p67 = (((zm >> 6) & 1u) ? wr[6] : 0.f) + (((zm >> 7) & 1u) ? wr[7] : 0.f);
      float p89 = (((zm >> 8) & 1u) ? wr[8] : 0.f) + (((zm >> 9) & 1u) ? wr[9] : 0.f);
      float rec = ((p01 + p23) + (p45 + p67)) + p89;
      float i_jump = (cur + iin) + rec;
      float v_dec = fmaf(0.1f, i_jump - vm, vm);  // vm + 0.1*(i_jump - vm)
      cur = 0.8f * i_jump;                        // i_dec
      bool z = v_dec > 0.5f;
      vm = z ? 0.f : v_dec;
      S += z ? gt : 0.f;
      zm = (unsigned)__ballot(z) & 0x3FFu;
    };

    float ibuf[8];
#pragma unroll
    for (int u = 0; u < 8; ++u) ibuf[u] = slab[u * 11 + slot];
    float4 gA = *(const float4*)&gtab[0], gB = *(const float4*)&gtab[4];

    for (int t8 = 0; t8 < T - 8; t8 += 8) {
      float4 nA = *(const float4*)&gtab[t8 + 8];
      float4 nB = *(const float4*)&gtab[t8 + 12];
      step(ibuf[0], gA.x); ibuf[0] = slab[(t8 +  8) * 11 + slot];
      step(ibuf[1], gA.y); ibuf[1] = slab[(t8 +  9) * 11 + slot];
      step(ibuf[2], gA.z); ibuf[2] = slab[(t8 + 10) * 11 + slot];
      step(ibuf[3], gA.w); ibuf[3] = slab[(t8 + 11) * 11 + slot];
      step(ibuf[4], gB.x); ibuf[4] = slab[(t8 + 12) * 11 + slot];
      step(ibuf[5], gB.y); ibuf[5] = slab[(t8 + 13) * 11 + slot];
      step(ibuf[6], gB.z); ibuf[6] = slab[(t8 + 14) * 11 + slot];
      step(ibuf[7], gB.w); ibuf[7] = slab[(t8 + 15) * 11 + slot];
      gA = nA; gB = nB;
    }
    step(ibuf[0], gA.x); step(ibuf[1], gA.y);
    step(ibuf[2], gA.z); step(ibuf[3], gA.w);
    step(ibuf[4], gB.x); step(ibuf[5], gB.y);
    step(ibuf[6], gB.z); step(ibuf[7], gB.w);

    int li = lane < H ? lane : 0;
    float c0 = (lane < H) ? S * p.W_cls[li]     : 0.f;
    float c1 = (lane < H) ? S * p.W_cls[H + li] : 0.f;
    float r0 = wred63(c0), r1 = wred63(c1);
    if (lane == 63) {
      p.out[b * 2 + 0] = r0 + gtot * p.b_cls[0];
      p.out[b * 2 + 1] = r1 + gtot * p.b_cls[1];
    }
  }
}

extern "C" void kernel_launch(void* const* d_in, const int* in_sizes, int n_in,
                              void* d_out, int out_size, void* d_ws, size_t ws_size,
                              hipStream_t stream) {
  Params p;
  p.beeg  = (const float*)d_in[2];
  p.W_ef  = (const float*)d_in[4];
  p.b_ef  = (const float*)d_in[5];
  p.g_i   = (const float*)d_in[6];
  p.be_i  = (const float*)d_in[7];
  p.Wq    = (const float*)d_in[8];
  p.g_q   = (const float*)d_in[9];
  p.be_q  = (const float*)d_in[10];
  p.Wk    = (const float*)d_in[11];
  p.g_k   = (const float*)d_in[12];
  p.be_k  = (const float*)d_in[13];
  p.Wv    = (const float*)d_in[14];
  p.g_v   = (const float*)d_in[15];
  p.be_v  = (const float*)d_in[16];
  p.Wc    = (const float*)d_in[17];
  p.g_c   = (const float*)d_in[18];
  p.be_c  = (const float*)d_in[19];
  p.W_in  = (const float*)d_in[20];
  p.W_rec = (const float*)d_in[21];
  p.W_cls = (const float*)d_in[22];
  p.b_cls = (const float*)d_in[23];

  char* ws = (char*)d_ws;
  p.cnt = (int*)ws;                            // 3 counters, memset below
  p.P1  = (double*)(ws + 256);                 // 32*20 doubles
  p.P2  = (double*)(ws + 256 + 5120);          // 32*60 doubles
  p.P3  = (double*)(ws + 256 + 5120 + 15360);  // 32*20 doubles
  p.out = (float*)d_out;

  (void)hipMemsetAsync(d_ws, 0, 256, stream);  // zero barrier counters
  fused9<<<dim3(B), dim3(NT), 0, stream>>>(p);
}

// Round 13
// 265.366 us; speedup vs baseline: 1.1431x; 1.0094x over previous
//
#include <hip/hip_runtime.h>
#include <math.h>

// Model: B=32, C=64, T=1024, H=10, OUT=2.
// ONE kernel, 32 blocks (one per batch element) x 512 threads; each thread
// owns TWO time-steps (t, t+512). S1 embed | S2 bn+tanh + qkv stats |
// S3 M=KV^T two passes | S4 N=M Wc^T/H, recompute q -> prec=q.N |
// S5 bn+relu -> Iin into LDS | S6 LSNN scan on wave 0 from LDS.
//
// R12 post-mortem: DPP+scalar weights got 196->167us, spills zero. Remaining
// stall suspect: the stats combines were SERIAL chains of 32 agent-scope
// atomic loads (uncached LLC round-trips, ~600-900cyc each, not batched by
// the backend) = ~8-15us per barrier x3.
// R13: P layout transposed to [channel][block]; combine parallelized --
// Q2x16 worker threads each issue 2 INDEPENDENT atomic loads (one parallel
// LLC hop), partials to LDS f64, 16-wide LDS reduce per channel.
// Plus #pragma unroll 8 on S1's load loop. All else identical to R12.

constexpr int B = 32, C = 64, T = 1024, H = 10;
constexpr int NT = 512;   // threads per block (8 waves)

struct Params {
  const float *beeg, *W_ef, *b_ef, *g_i, *be_i, *Wq, *g_q, *be_q, *Wk, *g_k,
      *be_k, *Wv, *g_v, *be_v, *Wc, *g_c, *be_c, *W_in, *W_rec, *W_cls, *b_cls;
  int* cnt;              // barrier counters (memset 0 each launch)
  double *P1, *P2, *P3;  // cross-block stat partials, layout [ch][32]
  float* out;
};

// DPP wave64 sum: result valid in lane 63 (VALU pipe, no DS traffic).
template <int CTRL>
__device__ inline float dadd(float v) {
  int x = __builtin_amdgcn_update_dpp(0, __float_as_int(v), CTRL, 0xf, 0xf,
                                      true);
  return v + __int_as_float(x);
}
__device__ inline float wred63(float v) {
  v = dadd<0x111>(v);  // row_shr:1
  v = dadd<0x112>(v);  // row_shr:2
  v = dadd<0x114>(v);  // row_shr:4
  v = dadd<0x118>(v);  // row_shr:8
  v = dadd<0x142>(v);  // row_bcast:15
  v = dadd<0x143>(v);  // row_bcast:31
  return v;            // lane 63 = full sum
}

// 32-block barrier, fence-free (all cross-block data via agent-scope atomics).
__device__ inline void gbar(int* cnt, int phase, int tid) {
  __syncthreads();
  if (tid == 0) {
    __hip_atomic_fetch_add(&cnt[phase], 1, __ATOMIC_RELEASE,
                           __HIP_MEMORY_SCOPE_AGENT);
    while (__hip_atomic_load(&cnt[phase], __ATOMIC_RELAXED,
                             __HIP_MEMORY_SCOPE_AGENT) < B)
      __builtin_amdgcn_s_sleep(2);
  }
  __syncthreads();
}

__global__ void __launch_bounds__(NT) fused10(Params p) {
  const int b = blockIdx.x, tid = threadIdx.x;
  const int lane = tid & 63, wid = tid >> 6;   // 8 waves
  const int t0 = tid, t1 = tid + NT;

  // LDS total ~58.5KB => 2 WGs/CU by the occupancy heuristic => 4 waves/EU
  // => 128-VGPR budget (keeps the no-spill regime of R8-R12).
  __shared__ __align__(16) float slab[T * 11];   // scratch then Iin (45KB)
  __shared__ __align__(16) float gtab[T];        // 4KB
  __shared__ double dred2[960];                  // parallel-combine partials
  __shared__ double dtot[60];
  __shared__ float stM[30], stI[30], Ms[100], Nl[100];

  float* swred = slab;         // [8][60] stats scratch (dead before S5)
  float* mpw   = slab + 512;   // [8][100] M partials (dead before S5)

  // g[t] = (9(1-0.9^{T-t}) - 4(1-0.8^{T-t})) / T  (f32 closed form)
  {
    const float L2A = -0.15200309344504995f;   // log2(0.9)
    const float L2D = -0.32192809488736235f;   // log2(0.8)
    float m0 = (float)(T - t0), m1 = (float)(T - t1);
    gtab[t0] = (9.0f * (1.0f - exp2f(m0 * L2A)) -
                4.0f * (1.0f - exp2f(m0 * L2D))) * (1.0f / (float)T);
    gtab[t1] = (9.0f * (1.0f - exp2f(m1 * L2A)) -
                4.0f * (1.0f - exp2f(m1 * L2D))) * (1.0f / (float)T);
  }

  // parallel stats combine: P layout [ch][32]; Q2x16 workers, 2 loads each.
  auto combine = [&](double* P, int Q2) {
    for (int id = tid; id < Q2 * 16; id += NT) {
      int ch = id >> 4, i = id & 15;
      double s = __hip_atomic_load(&P[ch * 32 + i], __ATOMIC_RELAXED,
                                   __HIP_MEMORY_SCOPE_AGENT) +
                 __hip_atomic_load(&P[ch * 32 + 16 + i], __ATOMIC_RELAXED,
                                   __HIP_MEMORY_SCOPE_AGENT);
      dred2[ch * 16 + i] = s;
    }
    __syncthreads();
    if (tid < Q2) {
      double s = 0.0;
#pragma unroll
      for (int i = 0; i < 16; ++i) s += dred2[tid * 16 + i];
      dtot[tid] = s;
    }
    __syncthreads();
  };

  // ---------------- S1: embed (weights via uniform/scalar loads)
  float p1a[H], p1b[H];
#pragma unroll
  for (int h = 0; h < H; ++h) { p1a[h] = p.b_ef[h]; p1b[h] = p.b_ef[h]; }
  {
    const float* bp = p.beeg + (size_t)b * C * T;
#pragma unroll 8
    for (int c = 0; c < C; ++c) {
      float va = bp[(size_t)c * T + t0];
      float vb = bp[(size_t)c * T + t1];
#pragma unroll
      for (int h = 0; h < H; ++h) {
        float w = p.W_ef[h * C + c];   // wave-uniform -> s_load
        p1a[h] = fmaf(va, w, p1a[h]);
        p1b[h] = fmaf(vb, w, p1b[h]);
      }
    }
  }
#pragma unroll
  for (int h = 0; h < H; ++h) {
    float r1 = wred63(p1a[h] + p1b[h]);
    float r2 = wred63(p1a[h] * p1a[h] + p1b[h] * p1b[h]);
    if (lane == 63) { swred[wid * 60 + h] = r1; swred[wid * 60 + 10 + h] = r2; }
  }
  __syncthreads();
  if (tid < 20) {
    float s = 0.f;
#pragma unroll
    for (int w = 0; w < 8; ++w) s += swred[w * 60 + tid];
    __hip_atomic_store(&p.P1[tid * 32 + b], (double)s, __ATOMIC_RELAXED,
                       __HIP_MEMORY_SCOPE_AGENT);
  }
  gbar(p.cnt, 0, tid);
  combine(p.P1, 20);
  if (tid < 10) {
    double mean = dtot[tid] * (1.0 / 32768.0);
    double var  = dtot[10 + tid] * (1.0 / 32768.0) - mean * mean;
    stM[tid] = (float)mean;
    stI[tid] = (float)(1.0 / sqrt(var + 1e-5));
  }
  __syncthreads();

  // ---------------- S2: x = tanh(bn(pre1)); qkv stats (accumulators only)
  float xa[H], xb[H];
#pragma unroll
  for (int j = 0; j < H; ++j) {
    xa[j] = tanhf(p.g_i[j] * (p1a[j] - stM[j]) * stI[j] + p.be_i[j]);
    xb[j] = tanhf(p.g_i[j] * (p1b[j] - stM[j]) * stI[j] + p.be_i[j]);
  }
  // p1a/p1b dead; only xa/xb (20 floats) persist from here on.
#pragma unroll
  for (int h = 0; h < H; ++h) {
    float qa = 0.f, qb = 0.f, ka = 0.f, kb = 0.f, va = 0.f, vb = 0.f;
#pragma unroll
    for (int j = 0; j < H; ++j) {
      float wq = p.Wq[h * H + j], wk = p.Wk[h * H + j], wv = p.Wv[h * H + j];
      qa = fmaf(xa[j], wq, qa); qb = fmaf(xb[j], wq, qb);
      ka = fmaf(xa[j], wk, ka); kb = fmaf(xb[j], wk, kb);
      va = fmaf(xa[j], wv, va); vb = fmaf(xb[j], wv, vb);
    }
    float r1 = wred63(qa + qb), r2 = wred63(qa * qa + qb * qb);
    float r3 = wred63(ka + kb), r4 = wred63(ka * ka + kb * kb);
    float r5 = wred63(va + vb), r6 = wred63(va * va + vb * vb);
    if (lane == 63) {
      swred[wid * 60 + h]      = r1; swred[wid * 60 + 30 + h] = r2;
      swred[wid * 60 + 10 + h] = r3; swred[wid * 60 + 40 + h] = r4;
      swred[wid * 60 + 20 + h] = r5; swred[wid * 60 + 50 + h] = r6;
    }
  }
  __syncthreads();
  if (tid < 60) {
    float s = 0.f;
#pragma unroll
    for (int w = 0; w < 8; ++w) s += swred[w * 60 + tid];
    __hip_atomic_store(&p.P2[tid * 32 + b], (double)s, __ATOMIC_RELAXED,
                       __HIP_MEMORY_SCOPE_AGENT);
  }
  gbar(p.cnt, 1, tid);
  combine(p.P2, 60);
  if (tid < 30) {
    double mean = dtot[tid] * (1.0 / 32768.0);
    double var  = dtot[30 + tid] * (1.0 / 32768.0) - mean * mean;
    stM[tid] = (float)mean;
    stI[tid] = (float)(1.0 / sqrt(var + 1e-5));
  }
  __syncthreads();

  // ---------------- S3: M = KV^T in two sequential passes (low pressure)
  {  // pass a
    float kx[H], vx[H];
#pragma unroll
    for (int h = 0; h < H; ++h) {
      float ka = 0.f, va = 0.f;
#pragma unroll
      for (int j = 0; j < H; ++j) {
        ka = fmaf(xa[j], p.Wk[h * H + j], ka);
        va = fmaf(xa[j], p.Wv[h * H + j], va);
      }
      kx[h] = fmaxf(p.g_k[h] * (ka - stM[10 + h]) * stI[10 + h] + p.be_k[h], 0.f);
      vx[h] = tanhf(p.g_v[h] * (va - stM[20 + h]) * stI[20 + h] + p.be_v[h]);
    }
#pragma unroll
    for (int i = 0; i < H; ++i)
#pragma unroll
      for (int j = 0; j < H; ++j) {
        float r = wred63(kx[i] * vx[j]);
        if (lane == 63) mpw[wid * 100 + i * 10 + j] = r;
      }
  }
  {  // pass b (accumulate)
    float kx[H], vx[H];
#pragma unroll
    for (int h = 0; h < H; ++h) {
      float kb = 0.f, vb = 0.f;
#pragma unroll
      for (int j = 0; j < H; ++j) {
        kb = fmaf(xb[j], p.Wk[h * H + j], kb);
        vb = fmaf(xb[j], p.Wv[h * H + j], vb);
      }
      kx[h] = fmaxf(p.g_k[h] * (kb - stM[10 + h]) * stI[10 + h] + p.be_k[h], 0.f);
      vx[h] = tanhf(p.g_v[h] * (vb - stM[20 + h]) * stI[20 + h] + p.be_v[h]);
    }
#pragma unroll
    for (int i = 0; i < H; ++i)
#pragma unroll
      for (int j = 0; j < H; ++j) {
        float r = wred63(kx[i] * vx[j]);
        if (lane == 63) mpw[wid * 100 + i * 10 + j] += r;
      }
  }
  __syncthreads();
  if (tid < 100) {
    float s = 0.f;
#pragma unroll
    for (int w = 0; w < 8; ++w) s += mpw[w * 100 + tid];
    Ms[tid] = s;
  }
  __syncthreads();

  // ---------------- S4: N = (M Wc^T)/H; recompute q; prec = q . N
  if (tid < 100) {
    int i = tid / 10, h = tid % 10;
    float a = 0.f;
#pragma unroll
    for (int j = 0; j < H; ++j) a = fmaf(Ms[i * 10 + j], p.Wc[h * H + j], a);
    Nl[tid] = a * 0.1f;
  }
  __syncthreads();
  float pca[H], pcb[H];
  {  // pass a
    float qv[H];
#pragma unroll
    for (int h = 0; h < H; ++h) {
      float qa = 0.f;
#pragma unroll
      for (int j = 0; j < H; ++j) qa = fmaf(xa[j], p.Wq[h * H + j], qa);
      qv[h] = fmaxf(p.g_q[h] * (qa - stM[h]) * stI[h] + p.be_q[h], 0.f);
    }
#pragma unroll
    for (int h = 0; h < H; ++h) {
      float a = 0.f;
#pragma unroll
      for (int i = 0; i < H; ++i) a = fmaf(qv[i], Nl[i * 10 + h], a);
      pca[h] = a;
    }
  }
  {  // pass b
    float qv[H];
#pragma unroll
    for (int h = 0; h < H; ++h) {
      float qb = 0.f;
#pragma unroll
      for (int j = 0; j < H; ++j) qb = fmaf(xb[j], p.Wq[h * H + j], qb);
      qv[h] = fmaxf(p.g_q[h] * (qb - stM[h]) * stI[h] + p.be_q[h], 0.f);
    }
#pragma unroll
    for (int h = 0; h < H; ++h) {
      float a = 0.f;
#pragma unroll
      for (int i = 0; i < H; ++i) a = fmaf(qv[i], Nl[i * 10 + h], a);
      pcb[h] = a;
    }
  }
  // xa/xb dead now; pca/pcb (20 floats) live.
#pragma unroll
  for (int h = 0; h < H; ++h) {
    float r1 = wred63(pca[h] + pcb[h]);
    float r2 = wred63(pca[h] * pca[h] + pcb[h] * pcb[h]);
    if (lane == 63) { swred[wid * 60 + h] = r1; swred[wid * 60 + 10 + h] = r2; }
  }
  __syncthreads();
  if (tid < 20) {
    float s = 0.f;
#pragma unroll
    for (int w = 0; w < 8; ++w) s += swred[w * 60 + tid];
    __hip_atomic_store(&p.P3[tid * 32 + b], (double)s, __ATOMIC_RELAXED,
                       __HIP_MEMORY_SCOPE_AGENT);
  }
  gbar(p.cnt, 2, tid);
  combine(p.P3, 20);
  if (tid < 10) {
    double mean = dtot[tid] * (1.0 / 32768.0);
    double var  = dtot[10 + tid] * (1.0 / 32768.0) - mean * mean;
    stM[tid] = (float)mean;
    stI[tid] = (float)(1.0 / sqrt(var + 1e-5));
  }
  __syncthreads();   // all slab-scratch reads done before S5 overwrites

  // ---------------- S5: bn+relu, Iin into LDS slab (stride 11)
  {
    float ca[H];
#pragma unroll
    for (int j = 0; j < H; ++j)
      ca[j] = fmaxf(p.g_c[j] * (pca[j] - stM[j]) * stI[j] + p.be_c[j], 0.f);
#pragma unroll
    for (int h = 0; h < H; ++h) {
      float a = 0.f;
#pragma unroll
      for (int j = 0; j < H; ++j) a = fmaf(ca[j], p.W_in[h * H + j], a);
      slab[t0 * 11 + h] = a;
    }
#pragma unroll
    for (int j = 0; j < H; ++j)
      ca[j] = fmaxf(p.g_c[j] * (pcb[j] - stM[j]) * stI[j] + p.be_c[j], 0.f);
#pragma unroll
    for (int h = 0; h < H; ++h) {
      float a = 0.f;
#pragma unroll
      for (int j = 0; j < H; ++j) a = fmaf(ca[j], p.W_in[h * H + j], a);
      slab[t1 * 11 + h] = a;
    }
  }
  __syncthreads();

  // ---------------- S6: LSNN scan, wave 0 only, from LDS
  if (tid < 64) {
    // gtot closed form: .9^1024/.8^1024 underflow -> (5*1024 - 81 + 16)/1024
    const float gtot = 4.9365234375f;

    const int slot = lane < H ? lane : 0;   // inactive lanes broadcast slot 0
    float wr[H];
#pragma unroll
    for (int j = 0; j < H; ++j)
      wr[j] = (lane < H) ? p.W_rec[lane * H + j] : 0.f;  // one-time global

    float cur = 0.f, vm = 0.f, S = 0.f;
    unsigned zm = 0u;

    auto step = [&](float iin, float gt) {
      float p01 = (((zm >> 0) & 1u) ? wr[0] : 0.f) + (((zm >> 1) & 1u) ? wr[1] : 0.f);
      float p23 = (((zm >> 2) & 1u) ? wr[2] : 0.f) + (((zm >> 3) & 1u) ? wr[3] : 0.f);
      float p45 = (((zm >> 4) & 1u) ? wr[4] : 0.f) + (((zm >> 5) & 1u) ? wr[5] : 0.f);
      float p67 = (((zm >> 6) & 1u) ? wr[6] : 0.f) + (((zm >> 7) & 1u) ? wr[7] : 0.f);
      float p89 = (((zm >> 8) & 1u) ? wr[8] : 0.f) + (((zm >> 9) & 1u) ? wr[9] : 0.f);
      float rec = ((p01 + p23) + (p45 + p67)) + p89;
      float i_jump = (cur + iin) + rec;
      float v_dec = fmaf(0.1f, i_jump - vm, vm);  // vm + 0.1*(i_jump - vm)
      cur = 0.8f * i_jump;                        // i_dec
      bool z = v_dec > 0.5f;
      vm = z ? 0.f : v_dec;
      S += z ? gt : 0.f;
      zm = (unsigned)__ballot(z) & 0x3FFu;
    };

    float ibuf[8];
#pragma unroll
    for (int u = 0; u < 8; ++u) ibuf[u] = slab[u * 11 + slot];
    float4 gA = *(const float4*)&gtab[0], gB = *(const float4*)&gtab[4];

    for (int t8 = 0; t8 < T - 8; t8 += 8) {
      float4 nA = *(const float4*)&gtab[t8 + 8];
      float4 nB = *(const float4*)&gtab[t8 + 12];
      step(ibuf[0], gA.x); ibuf[0] = slab[(t8 +  8) * 11 + slot];
      step(ibuf[1], gA.y); ibuf[1] = slab[(t8 +  9) * 11 + slot];
      step(ibuf[2], gA.z); ibuf[2] = slab[(t8 + 10) * 11 + slot];
      step(ibuf[3], gA.w); ibuf[3] = slab[(t8 + 11) * 11 + slot];
      step(ibuf[4], gB.x); ibuf[4] = slab[(t8 + 12) * 11 + slot];
      step(ibuf[5], gB.y); ibuf[5] = slab[(t8 + 13) * 11 + slot];
      step(ibuf[6], gB.z); ibuf[6] = slab[(t8 + 14) * 11 + slot];
      step(ibuf[7], gB.w); ibuf[7] = slab[(t8 + 15) * 11 + slot];
      gA = nA; gB = nB;
    }
    step(ibuf[0], gA.x); step(ibuf[1], gA.y);
    step(ibuf[2], gA.z); step(ibuf[3], gA.w);
    step(ibuf[4], gB.x); step(ibuf[5], gB.y);
    step(ibuf[6], gB.z); step(ibuf[7], gB.w);

    int li = lane < H ? lane : 0;
    float c0 = (lane < H) ? S * p.W_cls[li]     : 0.f;
    float c1 = (lane < H) ? S * p.W_cls[H + li] : 0.f;
    float r0 = wred63(c0), r1 = wred63(c1);
    if (lane == 63) {
      p.out[b * 2 + 0] = r0 + gtot * p.b_cls[0];
      p.out[b * 2 + 1] = r1 + gtot * p.b_cls[1];
    }
  }
}

extern "C" void kernel_launch(void* const* d_in, const int* in_sizes, int n_in,
                              void* d_out, int out_size, void* d_ws, size_t ws_size,
                              hipStream_t stream) {
  Params p;
  p.beeg  = (const float*)d_in[2];
  p.W_ef  = (const float*)d_in[4];
  p.b_ef  = (const float*)d_in[5];
  p.g_i   = (const float*)d_in[6];
  p.be_i  = (const float*)d_in[7];
  p.Wq    = (const float*)d_in[8];
  p.g_q   = (const float*)d_in[9];
  p.be_q  = (const float*)d_in[10];
  p.Wk    = (const float*)d_in[11];
  p.g_k   = (const float*)d_in[12];
  p.be_k  = (const float*)d_in[13];
  p.Wv    = (const float*)d_in[14];
  p.g_v   = (const float*)d_in[15];
  p.be_v  = (const float*)d_in[16];
  p.Wc    = (const float*)d_in[17];
  p.g_c   = (const float*)d_in[18];
  p.be_c  = (const float*)d_in[19];
  p.W_in  = (const float*)d_in[20];
  p.W_rec = (const float*)d_in[21];
  p.W_cls = (const float*)d_in[22];
  p.b_cls = (const float*)d_in[23];

  char* ws = (char*)d_ws;
  p.cnt = (int*)ws;                            // 3 counters, memset below
  p.P1  = (double*)(ws + 256);                 // [20][32] doubles
  p.P2  = (double*)(ws + 256 + 5120);          // [60][32] doubles
  p.P3  = (double*)(ws + 256 + 5120 + 15360);  // [20][32] doubles
  p.out = (float*)d_out;

  (void)hipMemsetAsync(d_ws, 0, 256, stream);  // zero barrier counters
  fused10<<<dim3(B), dim3(NT), 0, stream>>>(p);
}